// Round 6
// baseline (1468.027 us; speedup 1.0000x reference)
//
#include <hip/hip_runtime.h>
#include <hip/hip_fp16.h>

#define B_  32
#define T_  2048
#define I_  256
#define H_  128

typedef _Float16 f16;
typedef _Float16 f16x2 __attribute__((ext_vector_type(2)));
typedef _Float16 f16x4 __attribute__((ext_vector_type(4)));
typedef _Float16 f16x8 __attribute__((ext_vector_type(8)));
typedef float    f32x4 __attribute__((ext_vector_type(4)));

#if __has_builtin(__builtin_amdgcn_fdot2)
#define FDOT2(a, b, c) __builtin_amdgcn_fdot2((a), (b), (c), false)
#else
static __device__ __forceinline__ float FDOT2(f16x2 a, f16x2 b, float c) {
  return c + (float)a[0] * (float)b[0] + (float)a[1] * (float)b[1];
}
#endif

static __device__ __forceinline__ f16x2 asf16x2(unsigned u) {
  return __builtin_bit_cast(f16x2, u);
}

// sigmoid(x) = 1/(1+2^(-x*log2e))
static __device__ __forceinline__ float fast_sig(float x) {
  float e = __builtin_amdgcn_exp2f(-1.44269504089f * x);
  return __builtin_amdgcn_rcpf(1.0f + e);
}
static __device__ __forceinline__ float fast_tanh(float x) {
  float e = __builtin_amdgcn_exp2f(-2.88539008178f * x);
  return 2.0f * __builtin_amdgcn_rcpf(1.0f + e) - 1.0f;
}

// LDS-only barrier: do NOT drain vmcnt -- global prefetch loads and out[]
// stores float across steps.  sched_barrier(0) fences per rule #18.
#define BARRIER_LDS()                                   \
  __builtin_amdgcn_sched_barrier(0);                    \
  asm volatile("s_waitcnt lgkmcnt(0)" ::: "memory");    \
  __builtin_amdgcn_s_barrier();                         \
  __builtin_amdgcn_sched_barrier(0)

#define MFMA16(a, b, c) __builtin_amdgcn_mfma_f32_16x16x32_f16((a), (b), (c), 0, 0, 0)

// ---------------------------------------------------------------------------
// Kernel 1: xg[m][n] = sum_k x[m][k] * W'[n][k] + b_ih[n] + b_hh[n]
//   (unchanged -- ~85 us, not the bottleneck)
// ---------------------------------------------------------------------------
__global__ __launch_bounds__(256) void xg_gemm(
    const float* __restrict__ x,
    const float* __restrict__ Wf, const float* __restrict__ Wb,
    const float* __restrict__ bf_ih, const float* __restrict__ bf_hh,
    const float* __restrict__ bb_ih, const float* __restrict__ bb_hh,
    f16* __restrict__ xg)
{
  __shared__ f16 xs[128][136];   // +8 f16 pad
  __shared__ f16 wt[128][136];

  const int tid = threadIdx.x;
  const int m0  = blockIdx.y * 128;
  const int n0  = blockIdx.x * 128;

  const float* Wsrc; const float* bih; const float* bhh; int nb;
  if (n0 < 512) { Wsrc = Wf; bih = bf_ih; bhh = bf_hh; nb = n0; }
  else          { Wsrc = Wb; bih = bb_ih; bhh = bb_hh; nb = n0 - 512; }

  const int w  = tid >> 6;
  const int l  = tid & 63;
  const int lr = l & 15;
  const int lk = (l >> 4) * 8;

  f32x4 acc[2][8] = {};

  #pragma unroll
  for (int kh = 0; kh < 2; ++kh) {
    #pragma unroll
    for (int it = 0; it < 16; ++it) {
      int idx = it * 256 + tid;
      int row = idx >> 5, c4 = idx & 31;
      float4 v = *(const float4*)&x[(size_t)(m0 + row) * I_ + kh * 128 + c4 * 4];
      f16x4 h4 = { (f16)v.x, (f16)v.y, (f16)v.z, (f16)v.w };
      *(f16x4*)&xs[row][c4 * 4] = h4;
    }
    #pragma unroll
    for (int it = 0; it < 16; ++it) {
      int idx = it * 256 + tid;
      int row = idx >> 5, c4 = idx & 31;
      float4 v = *(const float4*)&Wsrc[(size_t)(nb + row) * I_ + kh * 128 + c4 * 4];
      f16x4 h4 = { (f16)v.x, (f16)v.y, (f16)v.z, (f16)v.w };
      *(f16x4*)&wt[row][c4 * 4] = h4;
    }
    __syncthreads();

    #pragma unroll
    for (int ks = 0; ks < 4; ++ks) {
      int kk = ks * 32 + lk;
      f16x8 a0 = *(const f16x8*)&xs[w * 32 + lr][kk];
      f16x8 a1 = *(const f16x8*)&xs[w * 32 + 16 + lr][kk];
      #pragma unroll
      for (int nt = 0; nt < 8; ++nt) {
        f16x8 bf = *(const f16x8*)&wt[nt * 16 + lr][kk];
        acc[0][nt] = MFMA16(a0, bf, acc[0][nt]);
        acc[1][nt] = MFMA16(a1, bf, acc[1][nt]);
      }
    }
    __syncthreads();
  }

  #pragma unroll
  for (int mt = 0; mt < 2; ++mt) {
    #pragma unroll
    for (int nt = 0; nt < 8; ++nt) {
      int nloc = nt * 16 + lr;
      float bias = bih[nb + nloc] + bhh[nb + nloc];
      #pragma unroll
      for (int r = 0; r < 4; ++r) {
        int m = m0 + w * 32 + mt * 16 + (l >> 4) * 4 + r;
        xg[(size_t)m * 1024 + n0 + nloc] = (f16)(acc[mt][nt][r] + bias);
      }
    }
  }
}

// ---------------------------------------------------------------------------
// Kernel 2: recurrence, half-row split, all exchanges intra-wave.
//   64 WGs x 512 thr (8 waves, 2 waves/SIMD).  Wave w, lane l:
//     unit u   = w*16 + ((l&31)>>1)
//     role rho = l>>5   (0: rows {u, 256+u} = (i,g);  1: {128+u, 384+u} = (f,o))
//     half hh  = l&1    (h elements [hh*64, hh*64+64))
//   Per thread: 64 weight f16x2 regs (fits in VGPR -- no AGPR round-trips),
//   64 FDOT2/step, 8 ds_read_b128 h-broadcast.  Half-combine: shfl_xor(1).
//   Role exchange: shfl_xor(32).  All 4 copies of a unit redundantly compute
//   c (convergent); the (rho=0,hh=0) lane writes h and out.
//   ONE LDS-only barrier per step, double-buffered h.
// ---------------------------------------------------------------------------
__global__ __launch_bounds__(512, 2) void birnn_rec(
    const f16* __restrict__ xg,
    const float* __restrict__ Wfhh, const float* __restrict__ Wbhh,
    const int* __restrict__ lengths,
    float* __restrict__ out)
{
  const int tid  = threadIdx.x;
  const int w    = tid >> 6;
  const int l    = tid & 63;
  const int hh   = l & 1;                    // h half
  const int role = l >> 5;                   // 0:(i,g)  1:(f,o)
  const int ul   = w * 16 + ((l & 31) >> 1); // unit index
  const int dir  = blockIdx.x >> 5;
  const int b    = blockIdx.x & 31;
  const float* Whh = dir ? Wbhh : Wfhh;
  const int L    = lengths[b];

  const int rowA = role ? (128 + ul) : ul;   // i or f
  const int rowB = rowA + 256;               // g or o

  // W_hh half-rows -> f16x2 register arrays (32 words each, fully unrolled)
  unsigned w0[32], w1[32];
  #pragma unroll
  for (int j = 0; j < 16; ++j) {
    float4 v = *(const float4*)&Whh[(size_t)rowA * H_ + hh * 64 + j * 4];
    w0[2 * j]     = __builtin_bit_cast(unsigned, (f16x2){ (f16)v.x, (f16)v.y });
    w0[2 * j + 1] = __builtin_bit_cast(unsigned, (f16x2){ (f16)v.z, (f16)v.w });
    float4 u = *(const float4*)&Whh[(size_t)rowB * H_ + hh * 64 + j * 4];
    w1[2 * j]     = __builtin_bit_cast(unsigned, (f16x2){ (f16)u.x, (f16)u.y });
    w1[2 * j + 1] = __builtin_bit_cast(unsigned, (f16x2){ (f16)u.z, (f16)u.w });
  }

  __shared__ __align__(16) f16 hbuf[2][128];   // h broadcast, double-buffered
  if (tid < 128) hbuf[0][tid] = (f16)0.0f;
  float c = 0.0f;
  __syncthreads();

  auto rowof = [&](int t) -> size_t {
    int it = t;
    if (dir) it = (t < L) ? (L - 1 - t) : t;
    return ((size_t)(b * T_ + it)) * 1024 + (size_t)dir * 512;
  };

  // depth-2 xg prefetch (named slots)
  f16 pa0, pa1, pb0, pb1;
  { size_t r = rowof(0); pa0 = xg[r + rowA]; pa1 = xg[r + rowB]; }
  { size_t r = rowof(1); pb0 = xg[r + rowA]; pb1 = xg[r + rowB]; }

  // role-blend for the "B" gate: role0 -> tanh(x) = 2*sig(2x)-1, role1 -> sig(x)
  const float bscale = role ? 1.0f : 2.0f;
  const float bmul   = role ? 1.0f : 2.0f;
  const float badd   = role ? 0.0f : -1.0f;
  const bool  writer = ((l & 33) == 0);      // hh==0 && role==0

#define STEP(t, P0, P1, RB, WB)                                              \
  {                                                                          \
    /* halves contribute; full xg only from hh==0 lane (hh==1 adds 0) */     \
    float aA[4] = { hh ? 0.f : (float)(P0), 0.f, 0.f, 0.f };                 \
    float aB[4] = { hh ? 0.f : (float)(P1), 0.f, 0.f, 0.f };                 \
    if ((t) + 2 < T_) {                                                      \
      size_t r2 = rowof((t) + 2);                                            \
      (P0) = xg[r2 + rowA];                                                  \
      (P1) = xg[r2 + rowB];                                                  \
    }                                                                        \
    _Pragma("unroll")                                                        \
    for (int j4 = 0; j4 < 8; ++j4) {                                         \
      uint4 hv = *(const uint4*)&hbuf[RB][hh * 64 + j4 * 8];                 \
      aA[0] = FDOT2(asf16x2(hv.x), asf16x2(w0[j4 * 4 + 0]), aA[0]);          \
      aB[0] = FDOT2(asf16x2(hv.x), asf16x2(w1[j4 * 4 + 0]), aB[0]);          \
      aA[1] = FDOT2(asf16x2(hv.y), asf16x2(w0[j4 * 4 + 1]), aA[1]);          \
      aB[1] = FDOT2(asf16x2(hv.y), asf16x2(w1[j4 * 4 + 1]), aB[1]);          \
      aA[2] = FDOT2(asf16x2(hv.z), asf16x2(w0[j4 * 4 + 2]), aA[2]);          \
      aB[2] = FDOT2(asf16x2(hv.z), asf16x2(w1[j4 * 4 + 2]), aB[2]);          \
      aA[3] = FDOT2(asf16x2(hv.w), asf16x2(w0[j4 * 4 + 3]), aA[3]);          \
      aB[3] = FDOT2(asf16x2(hv.w), asf16x2(w1[j4 * 4 + 3]), aB[3]);          \
    }                                                                        \
    float sumA = (aA[0] + aA[1]) + (aA[2] + aA[3]);                          \
    float sumB = (aB[0] + aB[1]) + (aB[2] + aB[3]);                          \
    /* combine h halves: partner lane l^1 */                                 \
    sumA += __shfl_xor(sumA, 1, 64);                                         \
    sumB += __shfl_xor(sumB, 1, 64);                                         \
    /* activations: sA sig both roles; sB role0 tanh, role1 sig */           \
    float sA = fast_sig(sumA);                                               \
    float sB = fast_sig(bscale * sumB) * bmul + badd;                        \
    /* role exchange: partner lane l^32 */                                   \
    float pA = __shfl_xor(sA, 32, 64);                                       \
    float pB = __shfl_xor(sB, 32, 64);                                       \
    float is_ = role ? pA : sA;                                              \
    float gt_ = role ? pB : sB;                                              \
    float fs_ = role ? sA : pA;                                              \
    float os_ = role ? sB : pB;                                              \
    c = fs_ * c + is_ * gt_;                                                 \
    float hval = os_ * fast_tanh(c);                                         \
    if (writer) {                                                            \
      hbuf[WB][ul] = (f16)hval;                                              \
      out[((size_t)(b * T_ + (t))) * 256 + dir * 128 + ul] = hval;           \
    }                                                                        \
    BARRIER_LDS();                                                           \
  }

  for (int tt = 0; tt < T_; tt += 2) {
    STEP(tt,     pa0, pa1, 0, 1);
    STEP(tt + 1, pb0, pb1, 1, 0);
  }
#undef STEP
}

// ---------------------------------------------------------------------------
extern "C" void kernel_launch(void* const* d_in, const int* in_sizes, int n_in,
                              void* d_out, int out_size, void* d_ws, size_t ws_size,
                              hipStream_t stream) {
  const float* x      = (const float*)d_in[0];
  const int*   lengths= (const int*)  d_in[1];
  const float* Wf_ih  = (const float*)d_in[2];
  const float* Wf_hh  = (const float*)d_in[3];
  const float* bf_ih  = (const float*)d_in[4];
  const float* bf_hh  = (const float*)d_in[5];
  const float* Wb_ih  = (const float*)d_in[6];
  const float* Wb_hh  = (const float*)d_in[7];
  const float* bb_ih  = (const float*)d_in[8];
  const float* bb_hh  = (const float*)d_in[9];
  float* out = (float*)d_out;
  f16*   xg  = (f16*)d_ws;   // needs B*T*1024*2 = 134,217,728 bytes

  (void)in_sizes; (void)n_in; (void)out_size; (void)ws_size;

  xg_gemm<<<dim3(8, 512), 256, 0, stream>>>(x, Wf_ih, Wb_ih,
                                            bf_ih, bf_hh, bb_ih, bb_hh, xg);
  birnn_rec<<<dim3(64), 512, 0, stream>>>(xg, Wf_hh, Wb_hh, lengths, out);
}